// Round 6
// baseline (425.989 us; speedup 1.0000x reference)
//
#include <hip/hip_runtime.h>
#include <math.h>

#define Bz 32
#define Lz 2048
#define Hz 768
#define Tz 12
#define Ez 7
#define EMPTYIDX 6
#define NCOL 24              // T*2 logit columns per batch
#define NITEM (Bz * Tz)      // 384 (b,t) pairs
#define LCHUNK 64
#define NCHUNK 32            // Lz / LCHUNK -> grid 1024 = 4 blocks/CU

// ---------------- kernel 0: bin (b,t) pairs by module index e ----------------
__global__ void k0_compact(const int* __restrict__ midx,
                           int* __restrict__ off, int* __restrict__ items) {
    __shared__ int cnt[Ez];
    __shared__ int offs[Ez + 1];
    int tid = threadIdx.x;                 // 384 threads, one per (b,t)
    if (tid < Ez) cnt[tid] = 0;
    __syncthreads();
    int e = midx[tid];
    e = min(max(e, 0), Ez - 1);
    int r = atomicAdd(&cnt[e], 1);
    __syncthreads();
    if (tid == 0) {
        int acc = 0;
        for (int j = 0; j < Ez; ++j) { offs[j] = acc; acc += cnt[j]; }
        offs[Ez] = acc;
    }
    __syncthreads();
    items[offs[e] + r] = tid;
    if (tid <= Ez) off[tid] = offs[tid];
}

// ---------------- kernel 1a: cW partial dots, H split across blocks ----------
#define K1A_ZC 3
#define K1A_HB 48
#define K1A_HC 16
__global__ void k1a_cw(const float* __restrict__ seq, const float* __restrict__ W,
                       const int* __restrict__ turns,
                       const int* __restrict__ off, const int* __restrict__ items,
                       float* __restrict__ pc) {
    int bx = blockIdx.x;
    int e  = bx % Ez;
    int zc = (bx / Ez) % K1A_ZC;
    int hc = bx / (Ez * K1A_ZC);           // 0..15
    int z  = zc * 256 + threadIdx.x;       // 0..767
    int h0 = hc * K1A_HB;
    int off0 = off[e];
    int cnt  = off[e + 1] - off0;
    const float* Wb = W + ((size_t)e * Hz + h0) * Hz + z;
    float w[K1A_HB];
#pragma unroll
    for (int j = 0; j < K1A_HB; ++j) w[j] = Wb[(size_t)j * Hz];

    for (int n = 0; n < cnt; ++n) {
        int i  = items[off0 + n];          // wave-uniform in practice
        int b  = i / Tz;
        int st = turns[2 * i];
        st = min(max(st, 0), Lz - 1);
        const float* c = seq + ((size_t)(b * Lz + st)) * Hz + h0;
        float acc = 0.f;
#pragma unroll
        for (int j = 0; j < K1A_HB; ++j) acc = fmaf(c[j], w[j], acc);
        pc[((size_t)hc * NITEM + i) * Hz + z] = acc;   // disjoint -> plain store
    }
}

// ---------------- kernel 1b: reduce hc partials, v = cW * spanw --------------
__global__ void k1b_v(const float* __restrict__ pc, const float* __restrict__ spanw,
                      const int* __restrict__ midx, float* __restrict__ v) {
    int idx = blockIdx.x * 256 + threadIdx.x;   // 384*768 = 294912
    int i = idx / Hz;
    int z = idx - i * Hz;
    float cw = 0.f;
#pragma unroll
    for (int hc = 0; hc < K1A_HC; ++hc)
        cw += pc[((size_t)hc * NITEM + i) * Hz + z];
    int e = midx[i];
    e = min(max(e, 0), Ez - 1);
    int b = i / Tz, t = i - b * Tz;
    size_t vb = ((size_t)(b * NCOL + t * 2)) * Hz + z;
    v[vb]      = cw * spanw[(e * Hz + z) * 2 + 0];
    v[vb + Hz] = cw * spanw[(e * Hz + z) * 2 + 1];
}

// ---------------- kernel 2: logits GEMM + chunk logsumexp + picked -----------
// r5 diagnosis: still latency-bound -- 1 row/thread means each 16B V load
// feeds only 4 FMAs. This version: thread = (row-pair rp/rp+32, k-eighth
// kq=tid&7). V reuse doubled (1 load : 8 FMAs) and V loads are COALESCED
// (kq in lane index -> a wave covers one col's contiguous 256B k-slice)
// instead of 64-lane broadcasts. kq-merge via __shfl_xor butterfly
// (in-register, no LDS bufB/bufC). All state NAMED scalars (rule #20;
// WRITE_SIZE is the spill tripwire, 194MB->0.8MB proven r2->r4).
#define BKP 64               // k floats staged per phase
#define NPH (Hz / BKP)       // 12

typedef float4 F4;

#define C_LIST(X) X(0) X(1) X(2) X(3) X(4) X(5) X(6) X(7) X(8) X(9) X(10) X(11) \
                  X(12) X(13) X(14) X(15) X(16) X(17) X(18) X(19) X(20) X(21) X(22) X(23)

__global__ __launch_bounds__(256, 4)
void k2_logits(const float* __restrict__ seq, const float* __restrict__ v,
               const int* __restrict__ kps,
               float* __restrict__ pm, float* __restrict__ ps,
               float* __restrict__ picked) {
    int bx  = blockIdx.x;
    int b   = bx / NCHUNK;
    int ch  = bx % NCHUNK;
    int l0  = ch * LCHUNK;
    int tid = threadIdx.x;
    int rp  = tid >> 3;                    // 0..31: rows rp and rp+32
    int kq  = tid & 7;                     // k-eighth within phase (8 floats)

    __shared__ float at[LCHUNK][BKP];        // 16 KB, XOR-swizzled 16B groups
    __shared__ float lgbuf[LCHUNK][NCOL + 1];// merged logits, 6.4 KB
    __shared__ float redm[NCOL][4], reds[NCOL][4];
    __shared__ int   ksafe[NCOL];

    if (tid < NCOL) {
        int t0 = kps[b * NCOL + tid];
        ksafe[tid] = min(max(t0, 0), Lz - 1);
    }

#define DECL_ACC(n) float cA##n = 0.f; float cB##n = 0.f;
    C_LIST(DECL_ACC)
#undef DECL_ACC

    const float* A = seq + ((size_t)b * Lz + l0) * Hz;
    const float* V = v + (size_t)b * NCOL * Hz;

    // staging: thread (rb=tid>>4, cq=tid&15) stages rows rb+16p (p=0..3),
    // 16B group cq, into swizzled slot (cq ^ rb); (rb+16p)&15 == rb -> p-invariant.
    int rb   = tid >> 4;                   // 0..15
    int cq   = tid & 15;
    int slot = ((cq ^ rb) << 2);
    const float* Ab0 = A + (size_t)rb * Hz + (cq << 2);
    float* Sb = &at[0][0] + rb * BKP + slot;          // +1024 floats per p-step (16 rows)

    // phase-invariant LDS read addresses: this thread's 2 rows x 2 F4 (k-eighth kq)
    int rx = rp & 15;                       // (rp+32)&15 == rp&15
    const float* rowA = &at[rp][0];
    const float* rowB = &at[rp + 32][0];
    int s0 = (((2 * kq + 0) ^ rx) << 2);
    int s1 = (((2 * kq + 1) ^ rx) << 2);
    const float* apA0 = rowA + s0;  const float* apA1 = rowA + s1;
    const float* apB0 = rowB + s0;  const float* apB1 = rowB + s1;

    F4 g0, g1, g2, g3;
#define LOADG(KOFF) do { const float* Ap_ = Ab0 + (KOFF);            \
        g0 = *(const F4*)&Ap_[0 * 16 * Hz];                          \
        g1 = *(const F4*)&Ap_[1 * 16 * Hz];                          \
        g2 = *(const F4*)&Ap_[2 * 16 * Hz];                          \
        g3 = *(const F4*)&Ap_[3 * 16 * Hz]; } while (0)

    LOADG(0);                              // prologue: phase-0 loads

#pragma unroll 1
    for (int ph = 0; ph < NPH; ++ph) {
        __syncthreads();                   // prev compute done reading at
        *(F4*)&Sb[0 * 1024] = g0;  *(F4*)&Sb[1 * 1024] = g1;
        *(F4*)&Sb[2 * 1024] = g2;  *(F4*)&Sb[3 * 1024] = g3;
        __syncthreads();
        if (ph + 1 < NPH) LOADG((ph + 1) * BKP);   // hide HBM under compute

        F4 aA0 = *(const F4*)apA0, aA1 = *(const F4*)apA1;
        F4 aB0 = *(const F4*)apB0, aB1 = *(const F4*)apB1;

        const float* Vp = V + ph * BKP + kq * 8;    // per-lane; wave covers 256B
#define DO_COL(n) { const F4* vq_ = (const F4*)(Vp + (n) * Hz);       \
        F4 v0_ = vq_[0], v1_ = vq_[1];                                \
        cA##n = fmaf(aA0.x, v0_.x, cA##n); cA##n = fmaf(aA0.y, v0_.y, cA##n); \
        cA##n = fmaf(aA0.z, v0_.z, cA##n); cA##n = fmaf(aA0.w, v0_.w, cA##n); \
        cA##n = fmaf(aA1.x, v1_.x, cA##n); cA##n = fmaf(aA1.y, v1_.y, cA##n); \
        cA##n = fmaf(aA1.z, v1_.z, cA##n); cA##n = fmaf(aA1.w, v1_.w, cA##n); \
        cB##n = fmaf(aB0.x, v0_.x, cB##n); cB##n = fmaf(aB0.y, v0_.y, cB##n); \
        cB##n = fmaf(aB0.z, v0_.z, cB##n); cB##n = fmaf(aB0.w, v0_.w, cB##n); \
        cB##n = fmaf(aB1.x, v1_.x, cB##n); cB##n = fmaf(aB1.y, v1_.y, cB##n); \
        cB##n = fmaf(aB1.z, v1_.z, cB##n); cB##n = fmaf(aB1.w, v1_.w, cB##n); }
        C_LIST(DO_COL)
#undef DO_COL
    }
#undef LOADG

    // merge the 8 k-eighths: butterfly over lanes kq = tid&7 (same rp group)
#define RED(n) { cA##n += __shfl_xor(cA##n, 1); cA##n += __shfl_xor(cA##n, 2); \
                 cA##n += __shfl_xor(cA##n, 4);                                \
                 cB##n += __shfl_xor(cB##n, 1); cB##n += __shfl_xor(cB##n, 2); \
                 cB##n += __shfl_xor(cB##n, 4); }
    C_LIST(RED)
#undef RED

    __syncthreads();                       // everyone done with at / k-loop
    if (kq == 0) {                         // 32 threads own the 64 merged rows
        int g0r = l0 + rp, g1r = l0 + rp + 32;
#define MG(n) { lgbuf[rp][n] = cA##n; lgbuf[rp + 32][n] = cB##n;               \
                if (ksafe[n] == g0r) picked[b * NCOL + (n)] = cA##n;           \
                if (ksafe[n] == g1r) picked[b * NCOL + (n)] = cB##n; }
        C_LIST(MG)
#undef MG
    }
    __syncthreads();

    // chunk logsumexp partials: 96 threads = 24 cols x 4 row-quarters (16 rows)
    if (tid < 96) {
        int c = tid >> 2, rg = tid & 3;
        float m = lgbuf[rg * 16][c];
        for (int rr = rg * 16 + 1; rr < rg * 16 + 16; ++rr)
            m = fmaxf(m, lgbuf[rr][c]);
        float s = 0.f;
        for (int rr = rg * 16; rr < rg * 16 + 16; ++rr)
            s += expf(lgbuf[rr][c] - m);
        redm[c][rg] = m; reds[c][rg] = s;
    }
    __syncthreads();
    if (tid < NCOL) {
        float m = redm[tid][0];
        for (int j = 1; j < 4; ++j) m = fmaxf(m, redm[tid][j]);
        float s = 0.f;
        for (int j = 0; j < 4; ++j) s += reds[tid][j] * expf(redm[tid][j] - m);
        pm[((size_t)b * NCOL + tid) * NCHUNK + ch] = m;
        ps[((size_t)b * NCOL + tid) * NCHUNK + ch] = s;
    }
}

// ---------------- kernel 4: combine partials -> ce -> masked-mean loss -------
__global__ void k4_final(const int* __restrict__ midx, const int* __restrict__ turns,
                         const int* __restrict__ kps,
                         const float* __restrict__ pm, const float* __restrict__ ps,
                         const float* __restrict__ picked, float* __restrict__ out) {
    int tid = threadIdx.x;                 // 384 threads, one per (b,t)
    int i = tid;
    int b = i / Tz, t = i % Tz;
    int e = midx[i];
    float modm  = (e != EMPTYIDX) ? 1.f : 0.f;
    float tmask = (turns[2 * i] >= 0) ? 1.f : 0.f;
    float ce[2];
#pragma unroll
    for (int k = 0; k < 2; ++k) {
        int c = t * 2 + k;
        const float* pmr = pm + ((size_t)b * NCOL + c) * NCHUNK;
        const float* psr = ps + ((size_t)b * NCOL + c) * NCHUNK;
        float m = pmr[0];
        for (int chn = 1; chn < NCHUNK; ++chn) m = fmaxf(m, pmr[chn]);
        float s = 0.f;
        for (int chn = 0; chn < NCHUNK; ++chn) s += psr[chn] * expf(pmr[chn] - m);
        float lse = m + logf(s);
        int tgt = kps[2 * i + k];
        ce[k] = (tgt >= 0) ? (lse - picked[b * NCOL + c]) : 0.f;
    }
    float contrib = 0.5f * (ce[0] + ce[1]) * modm * tmask;

    __shared__ float wsum[6], wmask[6];
    float sl = contrib, sm = tmask;
    for (int o = 32; o > 0; o >>= 1) {
        sl += __shfl_down(sl, o, 64);
        sm += __shfl_down(sm, o, 64);
    }
    int w = tid >> 6, lane = tid & 63;
    if (lane == 0) { wsum[w] = sl; wmask[w] = sm; }
    __syncthreads();
    if (tid == 0) {
        float a = 0.f, mk = 0.f;
        for (int ww = 0; ww < 6; ++ww) { a += wsum[ww]; mk += wmask[ww]; }
        out[0] = a / mk;
    }
}

extern "C" void kernel_launch(void* const* d_in, const int* in_sizes, int n_in,
                              void* d_out, int out_size, void* d_ws, size_t ws_size,
                              hipStream_t stream) {
    const float* seq   = (const float*)d_in[0];  // (32,2048,768)
    const float* W     = (const float*)d_in[1];  // (7,768,768)
    const float* spanw = (const float*)d_in[2];  // (7,768,2)
    const int*   turns = (const int*)d_in[3];    // (32,12,2)
    const int*   kps   = (const int*)d_in[4];    // (32,12,2)
    const int*   midx  = (const int*)d_in[5];    // (32,12)
    float* out = (float*)d_out;

    char* ws = (char*)d_ws;
    int*   off    = (int*)(ws + 0);                              // 8 ints
    int*   items  = (int*)(ws + 256);                            // 384 ints
    float* pc     = (float*)(ws + 2048);                         // 16*384*768 f32 = 18,874,368 B
    float* v      = (float*)(ws + 2048 + 18874368);              // 32*24*768 f32 =  2,359,296 B
    float* pm     = (float*)(ws + 2048 + 18874368 + 2359296);            // 32*24*32 f32 = 98,304 B
    float* ps     = (float*)(ws + 2048 + 18874368 + 2359296 + 98304);    // 98,304 B
    float* picked = (float*)(ws + 2048 + 18874368 + 2359296 + 196608);   //  1,536 B

    hipLaunchKernelGGL(k0_compact, dim3(1), dim3(NITEM), 0, stream, midx, off, items);
    hipLaunchKernelGGL(k1a_cw, dim3(Ez * K1A_ZC * K1A_HC), dim3(256), 0, stream,
                       seq, W, turns, off, items, pc);
    hipLaunchKernelGGL(k1b_v, dim3((NITEM * Hz) / 256), dim3(256), 0, stream,
                       pc, spanw, midx, v);
    hipLaunchKernelGGL(k2_logits, dim3(Bz * NCHUNK), dim3(256), 0, stream,
                       seq, v, kps, pm, ps, picked);
    hipLaunchKernelGGL(k4_final, dim3(1), dim3(NITEM), 0, stream,
                       midx, turns, kps, pm, ps, picked, out);
}